// Round 5
// baseline (936.436 us; speedup 1.0000x reference)
//
#include <hip/hip_runtime.h>
#include <stdint.h>

#define GAS __attribute__((address_space(1)))
#define LAS __attribute__((address_space(3)))

typedef int v4i __attribute__((ext_vector_type(4)));

constexpr int Mdim = 8192;    // B*S = 4*2048
constexpr int Ndim = 16384;   // D_OUT
constexpr int Kdim = 4096;    // D_IN

__device__ __forceinline__ int pack4i8(int a, int b, int c, int d) {
    return (a & 255) | ((b & 255) << 8) | ((c & 255) << 16) | ((d & 255) << 24);
}

__device__ __forceinline__ int qz(float v, float inv) {
    return (int)fminf(fmaxf(rintf(v * inv), -128.0f), 127.0f);
}

// ---- pass 1: quantize x fp32 -> int8 (16 elems/thread) ----
__global__ void k_quant_x(const float* __restrict__ x, const float* __restrict__ asc,
                          int8_t* __restrict__ xq) {
    const int i = blockIdx.x * blockDim.x + threadIdx.x;
    const float inv = 1.0f / *asc;
    const float4* xv = (const float4*)x + (size_t)i * 4;
    float4 f0 = xv[0], f1 = xv[1], f2 = xv[2], f3 = xv[3];
    int4 o;
    o.x = pack4i8(qz(f0.x, inv), qz(f0.y, inv), qz(f0.z, inv), qz(f0.w, inv));
    o.y = pack4i8(qz(f1.x, inv), qz(f1.y, inv), qz(f1.z, inv), qz(f1.w, inv));
    o.z = pack4i8(qz(f2.x, inv), qz(f2.y, inv), qz(f2.z, inv), qz(f2.w, inv));
    o.w = pack4i8(qz(f3.x, inv), qz(f3.y, inv), qz(f3.z, inv), qz(f3.w, inv));
    ((int4*)xq)[i] = o;
}

// ---- pass 2: weight int32 (sign-extended int8) -> packed int8 ----
__global__ void k_conv_w(const int* __restrict__ w, int8_t* __restrict__ wq) {
    const int i = blockIdx.x * blockDim.x + threadIdx.x;
    const int4* wv = (const int4*)w + (size_t)i * 4;
    int4 a = wv[0], b = wv[1], c = wv[2], d = wv[3];
    int4 o;
    o.x = pack4i8(a.x, a.y, a.z, a.w);
    o.y = pack4i8(b.x, b.y, b.z, b.w);
    o.z = pack4i8(c.x, c.y, c.z, c.w);
    o.w = pack4i8(d.x, d.y, d.z, d.w);
    ((int4*)wq)[i] = o;
}

// ============================================================================
// pass 3 (main): 256(M) x 128(N) tile, 4 waves (2x2), wave tile 128x64.
// OCCUPANCY-FIRST: LDS = 2 slots x (A 16KB + B 8KB) = 48 KiB -> 2 blocks/CU
// (16 waves/CU). The two co-resident blocks have independent barriers, so one
// block's MFMA window overlaps the other's LDS-read/stage window (m114
// mechanism) — no intra-block pipelining needed.
// Per step: vmcnt(0); s_barrier; 12x ds_read_b128 (swizzled, conflict-free);
//           stage next tile (6x global_load_lds w16); lgkmcnt(0)+sched_barrier;
//           setprio(1) 32 MFMA setprio(0).
// Hazards: stage writes the opposite slot; its previous readers completed
// (lgkm-waited) before the barrier. vmcnt(0) drains loads issued 1 step
// (~1700 cy) earlier >= HBM latency.
// ============================================================================
constexpr int NSTEP = Kdim / 64;  // 64

__global__ __launch_bounds__(256, 2)
void k_gemm_pc(const int8_t* __restrict__ Aq, const int8_t* __restrict__ Bq,
               const float* __restrict__ wscale, const float* __restrict__ asc,
               const float* __restrict__ bias, float* __restrict__ out) {
    __shared__ __align__(16) int8_t lds[49152];  // slot s: A at s*24576, B at +16384
    const int tid = threadIdx.x, lane = tid & 63, w = tid >> 6;
    const int wm = w >> 1, wn = w & 1;              // 2M x 2N wave grid
    const int lrow = lane & 15, kgrp = lane >> 4;

    const int bid = blockIdx.x;                     // grid = 4096, %8 == 0
    const int swz = ((bid & 7) << 9) | (bid >> 3);  // bijective XCD swizzle
    const int mt = swz & 31, nt = swz >> 5;         // m fastest: share B panel
    const int m0 = mt << 8, n0 = nt << 7;

    // ---- staging geometry (swizzle involution verified rounds 2-4: 0 conflicts)
    // unit = 4 KB = 64 rows x 64 B; per thread 1 load/unit; A 4 units, B 2.
    const int srow = (w << 4) + (lane >> 2);        // row within unit, 0..63
    const int scol = (((lane & 3) ^ ((lane >> 3) & 3)) << 4);
    const int8_t* gA[4];
    const int8_t* gB[2];
#pragma unroll
    for (int u = 0; u < 4; ++u)
        gA[u] = Aq + (size_t)(m0 + u * 64 + srow) * Kdim + scol;
#pragma unroll
    for (int u = 0; u < 2; ++u)
        gB[u] = Bq + (size_t)(n0 + u * 64 + srow) * Kdim + scol;
    const int dstoff = w << 10;  // wave-uniform base; HW adds lane*16

    auto stage = [&](int slot, int kb) {
        int8_t* ba = lds + slot * 24576 + dstoff;
        int8_t* bb = ba + 16384;
#pragma unroll
        for (int u = 0; u < 2; ++u)
            __builtin_amdgcn_global_load_lds((const GAS void*)(gB[u] + kb),
                                             (LAS void*)(bb + u * 4096), 16, 0, 0);
#pragma unroll
        for (int u = 0; u < 4; ++u)
            __builtin_amdgcn_global_load_lds((const GAS void*)(gA[u] + kb),
                                             (LAS void*)(ba + u * 4096), 16, 0, 0);
    };

    // ---- read-side addressing (verified conflict-free) ----
    const int kc = (kgrp ^ ((lrow >> 1) & 3)) << 4;   // swizzled k-byte
    const int arowb = (((wm << 7) + lrow) << 6) + kc; // A row byte offset
    const int browb = (((wn << 6) + lrow) << 6) + kc; // B row byte offset

    v4i acc[8][4];
#pragma unroll
    for (int i = 0; i < 8; ++i)
#pragma unroll
        for (int j = 0; j < 4; ++j) acc[i][j] = (v4i){0, 0, 0, 0};

    v4i a[8], b[4];

    stage(0, 0);  // tile 0 -> slot 0
    int kb = 64;
    for (int s = 0; s < NSTEP; ++s) {
        asm volatile("s_waitcnt vmcnt(0)" ::: "memory");  // tile s staged (this wave)
        __builtin_amdgcn_s_barrier();                      // ...and by all waves
        __builtin_amdgcn_sched_barrier(0);
        const int8_t* As_ = lds + (s & 1) * 24576;
        const int8_t* Bs_ = As_ + 16384;
#pragma unroll
        for (int f = 0; f < 4; ++f)
            b[f] = *(const v4i*)(Bs_ + browb + f * 1024);
#pragma unroll
        for (int f = 0; f < 8; ++f)
            a[f] = *(const v4i*)(As_ + arowb + f * 1024);
        if (s < NSTEP - 1) { stage((s + 1) & 1, kb); kb += 64; }
        asm volatile("s_waitcnt lgkmcnt(0)" ::: "memory");
        __builtin_amdgcn_sched_barrier(0);                 // rule 18 fence
        __builtin_amdgcn_s_setprio(1);
#pragma unroll
        for (int fi = 0; fi < 8; ++fi)
#pragma unroll
            for (int fj = 0; fj < 4; ++fj)
                acc[fi][fj] = __builtin_amdgcn_mfma_i32_16x16x64_i8(a[fi], b[fj], acc[fi][fj], 0, 0, 0);
        __builtin_amdgcn_s_setprio(0);
    }

    // epilogue: y = i32 * (act_scale * wscale[n]) + bias[n]
    const float ascale = *asc;
#pragma unroll
    for (int fj = 0; fj < 4; ++fj) {
        const int col = n0 + (wn << 6) + fj * 16 + lrow;
        const float sc = ascale * wscale[col];
        const float bb = bias[col];
#pragma unroll
        for (int mi = 0; mi < 8; ++mi) {
            const int r0 = m0 + (wm << 7) + mi * 16 + (kgrp << 2);
            float* o = out + (size_t)r0 * Ndim + col;
#pragma unroll
            for (int q = 0; q < 4; ++q)
                o[(size_t)q * Ndim] = (float)acc[mi][fj][q] * sc + bb;
        }
    }
}

// ============================================================================
// fallback 128x128 kernel (only used if workspace is too small)
// ============================================================================
template <bool AQ, bool BQ>
__global__ __launch_bounds__(256)
void k_gemm(const int8_t* __restrict__ Aq, const float* __restrict__ Xf,
            const int8_t* __restrict__ Bq, const int* __restrict__ W32,
            const float* __restrict__ wscale, const float* __restrict__ asc,
            const float* __restrict__ bias, float* __restrict__ out) {
    constexpr int BM = 128, BN = 128, BK = 64;
    constexpr int KT = Kdim / BK;
    __shared__ __align__(16) int8_t As[2][BM * BK];
    __shared__ __align__(16) int8_t Bs[2][BN * BK];

    const int tid  = threadIdx.x;
    const int lane = tid & 63;
    const int wid  = tid >> 6;
    const int wm = wid >> 1, wn = wid & 1;
    const int lrow = lane & 15, kgrp = lane >> 4;

    const int cpx = gridDim.x >> 3;
    const int swz = ((int)blockIdx.x & 7) * cpx + ((int)blockIdx.x >> 3);
    const int mt = swz & (Mdim / BM - 1);
    const int nt = swz / (Mdim / BM);
    const int m0 = mt * BM, n0 = nt * BN;

    const float ascale = *asc;
    const float inv = 1.0f / ascale;

    v4i acc[4][4];
#pragma unroll
    for (int i = 0; i < 4; ++i)
#pragma unroll
        for (int j = 0; j < 4; ++j) acc[i][j] = (v4i){0, 0, 0, 0};

    auto stage = [&](int buf, int kt) {
        const int k0 = kt * BK;
        if constexpr (AQ) {
            int8_t* ldsp = &As[buf][wid << 10];
            const int8_t* g = Aq + (size_t)(m0 + (tid >> 2)) * Kdim + k0 + ((tid & 3) << 4);
            __builtin_amdgcn_global_load_lds((const GAS void*)g, (LAS void*)ldsp, 16, 0, 0);
            __builtin_amdgcn_global_load_lds((const GAS void*)(g + (size_t)64 * Kdim),
                                             (LAS void*)(ldsp + 4096), 16, 0, 0);
        } else {
            const int row = tid >> 1, cb = (tid & 1) << 5;
            const float4* src = (const float4*)(Xf + (size_t)(m0 + row) * Kdim + k0 + cb);
            int t[8];
#pragma unroll
            for (int j = 0; j < 8; ++j) {
                float4 f = src[j];
                t[j] = pack4i8(qz(f.x, inv), qz(f.y, inv), qz(f.z, inv), qz(f.w, inv));
            }
            int4* dst = (int4*)&As[buf][row * BK + cb];
            dst[0] = make_int4(t[0], t[1], t[2], t[3]);
            dst[1] = make_int4(t[4], t[5], t[6], t[7]);
        }
        if constexpr (BQ) {
            int8_t* ldsp = &Bs[buf][wid << 10];
            const int8_t* g = Bq + (size_t)(n0 + (tid >> 2)) * Kdim + k0 + ((tid & 3) << 4);
            __builtin_amdgcn_global_load_lds((const GAS void*)g, (LAS void*)ldsp, 16, 0, 0);
            __builtin_amdgcn_global_load_lds((const GAS void*)(g + (size_t)64 * Kdim),
                                             (LAS void*)(ldsp + 4096), 16, 0, 0);
        } else {
            const int row = tid >> 1, cb = (tid & 1) << 5;
            const int4* src = (const int4*)(W32 + (size_t)(n0 + row) * Kdim + k0 + cb);
            int t[8];
#pragma unroll
            for (int j = 0; j < 8; ++j) {
                int4 vv = src[j];
                t[j] = pack4i8(vv.x, vv.y, vv.z, vv.w);
            }
            int4* dst = (int4*)&Bs[buf][row * BK + cb];
            dst[0] = make_int4(t[0], t[1], t[2], t[3]);
            dst[1] = make_int4(t[4], t[5], t[6], t[7]);
        }
    };

    stage(0, 0);
    for (int kt = 0; kt < KT; ++kt) {
        const int cur = kt & 1;
        __syncthreads();
        if (kt + 1 < KT) stage(cur ^ 1, kt + 1);

        v4i a[4], b[4];
        const int koff = kgrp << 4;
#pragma unroll
        for (int i = 0; i < 4; ++i) {
            a[i] = *(const v4i*)&As[cur][(wm * 64 + i * 16 + lrow) * BK + koff];
            b[i] = *(const v4i*)&Bs[cur][(wn * 64 + i * 16 + lrow) * BK + koff];
        }
#pragma unroll
        for (int i = 0; i < 4; ++i)
#pragma unroll
            for (int j = 0; j < 4; ++j)
                acc[i][j] = __builtin_amdgcn_mfma_i32_16x16x64_i8(a[i], b[j], acc[i][j], 0, 0, 0);
    }

#pragma unroll
    for (int j = 0; j < 4; ++j) {
        const int col = n0 + wn * 64 + j * 16 + lrow;
        const float sc = ascale * wscale[col];
        const float bb = bias[col];
#pragma unroll
        for (int i = 0; i < 4; ++i) {
            const int r0 = m0 + wm * 64 + i * 16 + (kgrp << 2);
            float* o = out + (size_t)r0 * Ndim + col;
#pragma unroll
            for (int r = 0; r < 4; ++r)
                o[(size_t)r * Ndim] = (float)acc[i][j][r] * sc + bb;
        }
    }
}

extern "C" void kernel_launch(void* const* d_in, const int* in_sizes, int n_in,
                              void* d_out, int out_size, void* d_ws, size_t ws_size,
                              hipStream_t stream) {
    const float* x      = (const float*)d_in[0];
    const int*   w32    = (const int*)d_in[1];   // int8 values sign-extended to int32
    const float* wscale = (const float*)d_in[2];
    const float* asc    = (const float*)d_in[3];
    const float* bias   = (const float*)d_in[4];
    float* out = (float*)d_out;

    const size_t nx = (size_t)Mdim * Kdim;  // 33,554,432 B for x_int8
    const size_t nw = (size_t)Ndim * Kdim;  // 67,108,864 B for w_int8
    int8_t* xq = (int8_t*)d_ws;
    int8_t* wq = xq + nx;

    const bool haveX = ws_size >= nx;
    const bool haveW = ws_size >= nx + nw;

    if (haveX) k_quant_x<<<(int)(nx / 16 / 256), 256, 0, stream>>>(x, asc, xq);
    if (haveW) k_conv_w<<<(int)(nw / 16 / 256), 256, 0, stream>>>(w32, wq);

    if (haveW) {
        dim3 grid((Mdim / 256) * (Ndim / 128));  // 4096
        k_gemm_pc<<<grid, 256, 0, stream>>>(xq, wq, wscale, asc, bias, out);
    } else if (haveX) {
        dim3 grid((Mdim / 128) * (Ndim / 128));  // 8192
        k_gemm<true, false><<<grid, 256, 0, stream>>>(xq, x, wq, w32, wscale, asc, bias, out);
    } else {
        dim3 grid((Mdim / 128) * (Ndim / 128));
        k_gemm<false, false><<<grid, 256, 0, stream>>>(xq, x, wq, w32, wscale, asc, bias, out);
    }
}

// Round 6
// 830.130 us; speedup vs baseline: 1.1281x; 1.1281x over previous
//
#include <hip/hip_runtime.h>
#include <stdint.h>

#define GAS __attribute__((address_space(1)))
#define LAS __attribute__((address_space(3)))

typedef int v4i __attribute__((ext_vector_type(4)));

constexpr int Mdim = 8192;    // B*S = 4*2048
constexpr int Ndim = 16384;   // D_OUT
constexpr int Kdim = 4096;    // D_IN

__device__ __forceinline__ int pack4i8(int a, int b, int c, int d) {
    return (a & 255) | ((b & 255) << 8) | ((c & 255) << 16) | ((d & 255) << 24);
}

__device__ __forceinline__ int qz(float v, float inv) {
    return (int)fminf(fmaxf(rintf(v * inv), -128.0f), 127.0f);
}

// ---- pass 1: quantize x fp32 -> int8 (16 elems/thread) ----
__global__ void k_quant_x(const float* __restrict__ x, const float* __restrict__ asc,
                          int8_t* __restrict__ xq) {
    const int i = blockIdx.x * blockDim.x + threadIdx.x;
    const float inv = 1.0f / *asc;
    const float4* xv = (const float4*)x + (size_t)i * 4;
    float4 f0 = xv[0], f1 = xv[1], f2 = xv[2], f3 = xv[3];
    int4 o;
    o.x = pack4i8(qz(f0.x, inv), qz(f0.y, inv), qz(f0.z, inv), qz(f0.w, inv));
    o.y = pack4i8(qz(f1.x, inv), qz(f1.y, inv), qz(f1.z, inv), qz(f1.w, inv));
    o.z = pack4i8(qz(f2.x, inv), qz(f2.y, inv), qz(f2.z, inv), qz(f2.w, inv));
    o.w = pack4i8(qz(f3.x, inv), qz(f3.y, inv), qz(f3.z, inv), qz(f3.w, inv));
    ((int4*)xq)[i] = o;
}

// ---- pass 2: weight int32 (sign-extended int8) -> packed int8 ----
__global__ void k_conv_w(const int* __restrict__ w, int8_t* __restrict__ wq) {
    const int i = blockIdx.x * blockDim.x + threadIdx.x;
    const int4* wv = (const int4*)w + (size_t)i * 4;
    int4 a = wv[0], b = wv[1], c = wv[2], d = wv[3];
    int4 o;
    o.x = pack4i8(a.x, a.y, a.z, a.w);
    o.y = pack4i8(b.x, b.y, b.z, b.w);
    o.z = pack4i8(c.x, c.y, c.z, c.w);
    o.w = pack4i8(d.x, d.y, d.z, d.w);
    ((int4*)wq)[i] = o;
}

// ============================================================================
// pass 3 (main): byte-exact int8 port of the verified 256x256 8-phase
// template (m201, 62% MfmaUtil on bf16):
//   K-tile = 128 int8 (128 B/row). A = 32KB + B = 32KB per K-tile, 2-deep
//   double-buffer (buf = tile&1) = 128 KiB LDS. Iter = 2 K-tiles, 8 phases.
//   LDS layout per tile: [ks(2)][256 rows][64 B] so the verified
//   zero-conflict XOR swizzle (kc = (kgrp ^ ((lrow>>1)&3))<<4, inverse on
//   the global staging source) applies unchanged per 64-B k-sub.
//   Phase = { ds_read 4 B-frag (h0 only) + 4 A-frag ; stage 2 gloads ;
//             [vmcnt] ; s_barrier ; lgkmcnt(0)+sched_barrier ;
//             setprio(1) 16 MFMA setprio(0) ; s_barrier }.
//   Staging cadence (iter j, t0=2j, t1=2j+1):
//     ph1:A(t1,ks1) ph2:B(t0+2,ks0) ph3:A(t0+2,ks0) ph4:B(t0+2,ks1)
//     ph5:A(t0+2,ks1) ph6:B(t1+2,ks0) ph7:A(t1+2,ks0) ph8:B(t1+2,ks1)
//   Every stage targets a region whose last read was >=1 barrier earlier;
//   stage->first-read distance is 6-7 phases (~4000 cy >> HBM 900 cy).
//   vmcnt(10) at ph2/4/6/8 validates exactly the units first-read 1 phase
//   later (ledger in analysis). Last iter peeled: vmcnt(8)/(4)/(0).
// ============================================================================
constexpr int NT    = Kdim / 128;  // 32 K-tiles
constexpr int NITER = NT / 2;      // 16

#define VM10 asm volatile("s_waitcnt vmcnt(10)" ::: "memory")
#define VM8  asm volatile("s_waitcnt vmcnt(8)"  ::: "memory")
#define VM4  asm volatile("s_waitcnt vmcnt(4)"  ::: "memory")
#define VM0  asm volatile("s_waitcnt vmcnt(0)"  ::: "memory")

// one phase: optional B-frag read, 4 A-frag reads, stage, vmcnt, barrier,
// lgkm-fence, 16 MFMA, barrier.
#define PHASE(ABASE, BBASE, READB, AROW, ACC0, STAGE_STMT, VM_STMT)            \
  {                                                                            \
    if (READB) {                                                               \
      _Pragma("unroll") for (int f = 0; f < 4; ++f)                            \
          bfr[f] = *(const v4i*)(lds + (ABASE) + 32768 + browb + f * 1024);    \
    }                                                                          \
    _Pragma("unroll") for (int f = 0; f < 4; ++f)                              \
        afr[f] = *(const v4i*)(lds + (ABASE) + (AROW) + f * 1024);             \
    STAGE_STMT;                                                                \
    VM_STMT;                                                                   \
    __builtin_amdgcn_s_barrier();                                              \
    asm volatile("s_waitcnt lgkmcnt(0)" ::: "memory");                         \
    __builtin_amdgcn_sched_barrier(0);                                         \
    __builtin_amdgcn_s_setprio(1);                                             \
    _Pragma("unroll") for (int fi = 0; fi < 4; ++fi)                           \
        _Pragma("unroll") for (int fj = 0; fj < 4; ++fj)                       \
            acc[(ACC0) + fi][fj] = __builtin_amdgcn_mfma_i32_16x16x64_i8(      \
                afr[fi], bfr[fj], acc[(ACC0) + fi][fj], 0, 0, 0);              \
    __builtin_amdgcn_s_setprio(0);                                             \
    __builtin_amdgcn_s_barrier();                                              \
  }

__global__ __launch_bounds__(512, 2)
void k_gemm256(const int8_t* __restrict__ Aq, const int8_t* __restrict__ Bq,
               const float* __restrict__ wscale, const float* __restrict__ asc,
               const float* __restrict__ bias, float* __restrict__ out) {
    __shared__ __align__(16) int8_t lds[131072];
    const int tid = threadIdx.x, lane = tid & 63, w = tid >> 6;
    const int wm = w >> 2, wn = w & 3;              // 2M x 4N wave grid
    const int lrow = lane & 15, kgrp = lane >> 4;

    const int bid = blockIdx.x;                     // grid = 2048, %8 == 0
    const int swz = ((bid & 7) << 8) | (bid >> 3);  // bijective XCD swizzle
    const int mt = swz & 31, nt = swz >> 5;         // m fastest: share B panel
    const int m0 = mt << 8, n0 = nt << 8;

    // ---- staging geometry: 8KB unit = 128 rows x 64 B (one ks, one rb).
    // dest linear = tid*16; source col inverse-swizzled (verified 0-conflict).
    const int srow = tid >> 2;                      // row within 128-row unit
    const int scol = (((tid & 3) ^ ((tid >> 3) & 3)) << 4);
    const int8_t* rowA0 = Aq + (size_t)(m0 + srow) * Kdim + scol;
    const int8_t* rowB0 = Bq + (size_t)(n0 + srow) * Kdim + scol;
    const size_t rb1off = (size_t)128 * Kdim;
    const int dstoff = w << 10;                     // + HW lane*16

    // A(t,ks): buf=(t&1), region buf*65536 + ks*16384, rb0 then rb1(+8192)
    auto stA = [&](int t, int ks) {
        int8_t* d = lds + ((t & 1) << 16) + (ks << 14) + dstoff;
        const int8_t* s = rowA0 + t * 128 + ks * 64;
        __builtin_amdgcn_global_load_lds((const GAS void*)s, (LAS void*)d, 16, 0, 0);
        __builtin_amdgcn_global_load_lds((const GAS void*)(s + rb1off), (LAS void*)(d + 8192), 16, 0, 0);
    };
    auto stB = [&](int t, int ks) {
        int8_t* d = lds + ((t & 1) << 16) + 32768 + (ks << 14) + dstoff;
        const int8_t* s = rowB0 + t * 128 + ks * 64;
        __builtin_amdgcn_global_load_lds((const GAS void*)s, (LAS void*)d, 16, 0, 0);
        __builtin_amdgcn_global_load_lds((const GAS void*)(s + rb1off), (LAS void*)(d + 8192), 16, 0, 0);
    };

    // ---- read-side addressing (verified conflict-free swizzle) ----
    const int kc = (kgrp ^ ((lrow >> 1) & 3)) << 4;        // swizzled 16B slot
    const int arow0 = ((wm << 7) + lrow) * 64 + kc;        // h0 rows
    const int arow1 = ((wm << 7) + 64 + lrow) * 64 + kc;   // h1 rows
    const int browb = ((wn << 6) + lrow) * 64 + kc;

    v4i acc[8][4];
#pragma unroll
    for (int i = 0; i < 8; ++i)
#pragma unroll
        for (int j = 0; j < 4; ++j) acc[i][j] = (v4i){0, 0, 0, 0};

    v4i afr[4], bfr[4];

    // region bases: buf0 A=0 B=32768 ; buf1 A=65536 B=98304 (B handled in PHASE)
    // PHASE ABASE arg = buf*65536 + ks*16384.

    // prologue: everything of tiles 0,1 except A(1,ks1) (staged at iter0 ph1)
    stA(0, 0); stA(0, 1); stB(0, 0); stB(0, 1);
    stA(1, 0); stB(1, 0); stB(1, 1);
    VM0;
    __builtin_amdgcn_s_barrier();

    for (int j = 0; j < NITER - 1; ++j) {
        const int t0 = 2 * j, t1 = 2 * j + 1;
        // buf0, ks0
        PHASE(0,     0, true,  arow0, 0, stA(t1, 1),     );        // ph1
        PHASE(0,     0, false, arow1, 4, stB(t0 + 2, 0), VM10);    // ph2
        // buf0, ks1
        PHASE(16384, 0, true,  arow0, 0, stA(t0 + 2, 0), );        // ph3
        PHASE(16384, 0, false, arow1, 4, stB(t0 + 2, 1), VM10);    // ph4
        // buf1, ks0
        PHASE(65536, 0, true,  arow0, 0, stA(t0 + 2, 1), );        // ph5
        PHASE(65536, 0, false, arow1, 4, stB(t1 + 2, 0), VM10);    // ph6
        // buf1, ks1
        PHASE(81920, 0, true,  arow0, 0, stA(t1 + 2, 0), );        // ph7
        PHASE(81920, 0, false, arow1, 4, stB(t1 + 2, 1), VM10);    // ph8
    }

    // last iter (j = NITER-1 = 15): tiles 30,31; only ph1 stages (A(31,ks1));
    // tail vmcnts exact per ledger.
    {
        PHASE(0,     0, true,  arow0, 0, stA(31, 1), );            // ph1
        PHASE(0,     0, false, arow1, 4, ,           VM8);         // ph2
        PHASE(16384, 0, true,  arow0, 0, ,           );            // ph3
        PHASE(16384, 0, false, arow1, 4, ,           VM4);         // ph4
        PHASE(65536, 0, true,  arow0, 0, ,           );            // ph5
        PHASE(65536, 0, false, arow1, 4, ,           VM0);         // ph6
        PHASE(81920, 0, true,  arow0, 0, ,           );            // ph7
        PHASE(81920, 0, false, arow1, 4, ,           );            // ph8
    }

    // epilogue: y = i32 * (act_scale * wscale[n]) + bias[n]
    const float ascale = *asc;
#pragma unroll
    for (int fj = 0; fj < 4; ++fj) {
        const int col = n0 + (wn << 6) + fj * 16 + lrow;
        const float sc = ascale * wscale[col];
        const float bb = bias[col];
#pragma unroll
        for (int mi = 0; mi < 8; ++mi) {
            const int r0 = m0 + (wm << 7) + mi * 16 + (kgrp << 2);
            float* o = out + (size_t)r0 * Ndim + col;
#pragma unroll
            for (int q = 0; q < 4; ++q)
                o[(size_t)q * Ndim] = (float)acc[mi][fj][q] * sc + bb;
        }
    }
}

// ============================================================================
// fallback 128x128 kernel (only used if workspace is too small)
// ============================================================================
template <bool AQ, bool BQ>
__global__ __launch_bounds__(256)
void k_gemm(const int8_t* __restrict__ Aq, const float* __restrict__ Xf,
            const int8_t* __restrict__ Bq, const int* __restrict__ W32,
            const float* __restrict__ wscale, const float* __restrict__ asc,
            const float* __restrict__ bias, float* __restrict__ out) {
    constexpr int BM = 128, BN = 128, BK = 64;
    constexpr int KT = Kdim / BK;
    __shared__ __align__(16) int8_t As[2][BM * BK];
    __shared__ __align__(16) int8_t Bs[2][BN * BK];

    const int tid  = threadIdx.x;
    const int lane = tid & 63;
    const int wid  = tid >> 6;
    const int wm = wid >> 1, wn = wid & 1;
    const int lrow = lane & 15, kgrp = lane >> 4;

    const int cpx = gridDim.x >> 3;
    const int swz = ((int)blockIdx.x & 7) * cpx + ((int)blockIdx.x >> 3);
    const int mt = swz & (Mdim / BM - 1);
    const int nt = swz / (Mdim / BM);
    const int m0 = mt * BM, n0 = nt * BN;

    const float ascale = *asc;
    const float inv = 1.0f / ascale;

    v4i acc[4][4];
#pragma unroll
    for (int i = 0; i < 4; ++i)
#pragma unroll
        for (int j = 0; j < 4; ++j) acc[i][j] = (v4i){0, 0, 0, 0};

    auto stage = [&](int buf, int kt) {
        const int k0 = kt * BK;
        if constexpr (AQ) {
            int8_t* ldsp = &As[buf][wid << 10];
            const int8_t* g = Aq + (size_t)(m0 + (tid >> 2)) * Kdim + k0 + ((tid & 3) << 4);
            __builtin_amdgcn_global_load_lds((const GAS void*)g, (LAS void*)ldsp, 16, 0, 0);
            __builtin_amdgcn_global_load_lds((const GAS void*)(g + (size_t)64 * Kdim),
                                             (LAS void*)(ldsp + 4096), 16, 0, 0);
        } else {
            const int row = tid >> 1, cb = (tid & 1) << 5;
            const float4* src = (const float4*)(Xf + (size_t)(m0 + row) * Kdim + k0 + cb);
            int t[8];
#pragma unroll
            for (int j = 0; j < 8; ++j) {
                float4 f = src[j];
                t[j] = pack4i8(qz(f.x, inv), qz(f.y, inv), qz(f.z, inv), qz(f.w, inv));
            }
            int4* dst = (int4*)&As[buf][row * BK + cb];
            dst[0] = make_int4(t[0], t[1], t[2], t[3]);
            dst[1] = make_int4(t[4], t[5], t[6], t[7]);
        }
        if constexpr (BQ) {
            int8_t* ldsp = &Bs[buf][wid << 10];
            const int8_t* g = Bq + (size_t)(n0 + (tid >> 2)) * Kdim + k0 + ((tid & 3) << 4);
            __builtin_amdgcn_global_load_lds((const GAS void*)g, (LAS void*)ldsp, 16, 0, 0);
            __builtin_amdgcn_global_load_lds((const GAS void*)(g + (size_t)64 * Kdim),
                                             (LAS void*)(ldsp + 4096), 16, 0, 0);
        } else {
            const int row = tid >> 1, cb = (tid & 1) << 5;
            const int4* src = (const int4*)(W32 + (size_t)(n0 + row) * Kdim + k0 + cb);
            int t[8];
#pragma unroll
            for (int j = 0; j < 8; ++j) {
                int4 vv = src[j];
                t[j] = pack4i8(vv.x, vv.y, vv.z, vv.w);
            }
            int4* dst = (int4*)&Bs[buf][row * BK + cb];
            dst[0] = make_int4(t[0], t[1], t[2], t[3]);
            dst[1] = make_int4(t[4], t[5], t[6], t[7]);
        }
    };

    stage(0, 0);
    for (int kt = 0; kt < KT; ++kt) {
        const int cur = kt & 1;
        __syncthreads();
        if (kt + 1 < KT) stage(cur ^ 1, kt + 1);

        v4i a[4], b[4];
        const int koff = kgrp << 4;
#pragma unroll
        for (int i = 0; i < 4; ++i) {
            a[i] = *(const v4i*)&As[cur][(wm * 64 + i * 16 + lrow) * BK + koff];
            b[i] = *(const v4i*)&Bs[cur][(wn * 64 + i * 16 + lrow) * BK + koff];
        }
#pragma unroll
        for (int i = 0; i < 4; ++i)
#pragma unroll
            for (int j = 0; j < 4; ++j)
                acc[i][j] = __builtin_amdgcn_mfma_i32_16x16x64_i8(a[i], b[j], acc[i][j], 0, 0, 0);
    }

#pragma unroll
    for (int j = 0; j < 4; ++j) {
        const int col = n0 + wn * 64 + j * 16 + lrow;
        const float sc = ascale * wscale[col];
        const float bb = bias[col];
#pragma unroll
        for (int i = 0; i < 4; ++i) {
            const int r0 = m0 + wm * 64 + i * 16 + (kgrp << 2);
            float* o = out + (size_t)r0 * Ndim + col;
#pragma unroll
            for (int r = 0; r < 4; ++r)
                o[(size_t)r * Ndim] = (float)acc[i][j][r] * sc + bb;
        }
    }
}

extern "C" void kernel_launch(void* const* d_in, const int* in_sizes, int n_in,
                              void* d_out, int out_size, void* d_ws, size_t ws_size,
                              hipStream_t stream) {
    const float* x      = (const float*)d_in[0];
    const int*   w32    = (const int*)d_in[1];   // int8 values sign-extended to int32
    const float* wscale = (const float*)d_in[2];
    const float* asc    = (const float*)d_in[3];
    const float* bias   = (const float*)d_in[4];
    float* out = (float*)d_out;

    const size_t nx = (size_t)Mdim * Kdim;  // 33,554,432 B for x_int8
    const size_t nw = (size_t)Ndim * Kdim;  // 67,108,864 B for w_int8
    int8_t* xq = (int8_t*)d_ws;
    int8_t* wq = xq + nx;

    const bool haveX = ws_size >= nx;
    const bool haveW = ws_size >= nx + nw;

    if (haveX) k_quant_x<<<(int)(nx / 16 / 256), 256, 0, stream>>>(x, asc, xq);
    if (haveW) k_conv_w<<<(int)(nw / 16 / 256), 256, 0, stream>>>(w32, wq);

    if (haveW) {
        dim3 grid((Mdim / 256) * (Ndim / 256));  // 2048
        k_gemm256<<<grid, 512, 0, stream>>>(xq, wq, wscale, asc, bias, out);
    } else if (haveX) {
        dim3 grid((Mdim / 128) * (Ndim / 128));  // 8192
        k_gemm<true, false><<<grid, 256, 0, stream>>>(xq, x, wq, w32, wscale, asc, bias, out);
    } else {
        dim3 grid((Mdim / 128) * (Ndim / 128));
        k_gemm<false, false><<<grid, 256, 0, stream>>>(xq, x, wq, w32, wscale, asc, bias, out);
    }
}